// Round 7
// baseline (303.224 us; speedup 1.0000x reference)
//
#include <hip/hip_runtime.h>
#include <math.h>

typedef unsigned short u16;
typedef unsigned char u8;
typedef unsigned int u32;
typedef __attribute__((ext_vector_type(4))) float f32x4;
typedef __attribute__((ext_vector_type(8))) short s16x8;
typedef __attribute__((ext_vector_type(4))) short s16x4;
typedef __attribute__((ext_vector_type(4))) u32 u32x4;
typedef __attribute__((ext_vector_type(2))) u32 u32x2;

__device__ __forceinline__ u16 f2bf(float f) {
  unsigned u = __builtin_bit_cast(unsigned, f);
  u += 0x7fffu + ((u >> 16) & 1u);
  return (u16)(u >> 16);
}

__device__ __forceinline__ u32 cvtpk_bf16(float lo, float hi) {
  u32 r;
  asm("v_cvt_pk_bf16_f32 %0, %1, %2" : "=v"(r) : "v"(lo), "v"(hi));
  return r;
}

__device__ __forceinline__ float max3f(float a, float b, float c) {
  return fmaxf(fmaxf(a, b), c);  // fuses to v_max3_f32
}

#define GLDS16(g, l) __builtin_amdgcn_global_load_lds( \
    (const __attribute__((address_space(1))) void*)(g), \
    (__attribute__((address_space(3))) void*)(l), 16, 0, 0)

// ---------------- GEMM: C[M,N] = A[M,K](bf16) @ BT[N,K](bf16)^T ----------------
// 2-phase double-buffered staging. BM=128 (4 row-tiles/wave) or BM=64 (2).
// launch_bounds (256,2): R5-proven configuration (R6's (256,3) suspected in launch fail).
template <int EPI, int BM>
__global__ __launch_bounds__(256, 2) void gemm_bt(
    const u16* __restrict__ A, const u16* __restrict__ BT, int M, int N, int K,
    const float* __restrict__ bias, const float* __restrict__ resid,
    u16* __restrict__ outB, float* __restrict__ outF) {
  constexpr int MT = BM / 32;  // acc row-tiles per wave
  __shared__ __align__(16) u16 lA[2][BM * 32];
  __shared__ __align__(16) u16 lB[2][128 * 32];
  const int tid = threadIdx.x;
  const int wave = __builtin_amdgcn_readfirstlane(tid >> 6);
  const int lane = tid & 63;
  const int l15 = lane & 15, l4 = lane >> 4;
  const int wr = wave >> 1, wc = wave & 1;
  const int row0 = blockIdx.y * BM, col0 = blockIdx.x * 128;

  f32x4 acc[MT][4] = {};

  auto stage = [&](int bi, int k0) {
#pragma unroll
    for (int c = 0; c < BM / 64; ++c) {
      const int chunk = c * 4 + wave;          // 1KB chunks of A
      const int idx = chunk * 64 + lane;       // 16B-unit index
      const int r = idx >> 2, cb = (idx & 3) * 8;
      GLDS16(A + (size_t)(row0 + r) * K + k0 + cb, &lA[bi][chunk * 512]);
    }
#pragma unroll
    for (int c = 0; c < 2; ++c) {
      const int chunk = c * 4 + wave;
      const int idx = chunk * 64 + lane;
      const int r = idx >> 2, cb = (idx & 3) * 8;
      GLDS16(BT + (size_t)(col0 + r) * K + k0 + cb, &lB[bi][chunk * 512]);
    }
  };

  stage(0, 0);
  __syncthreads();
  int buf = 0;

  for (int k0 = 0; k0 < K; k0 += 32) {
    if (k0 + 32 < K) stage(buf ^ 1, k0 + 32);  // async prefetch, drained at loop-end barrier
    s16x8 af[MT], bfr[4];
#pragma unroll
    for (int m = 0; m < MT; ++m)
      af[m] = *(const s16x8*)&lA[buf][(wr * (BM / 2) + m * 16 + l15) * 32 + l4 * 8];
#pragma unroll
    for (int n = 0; n < 4; ++n)
      bfr[n] = *(const s16x8*)&lB[buf][(wc * 64 + n * 16 + l15) * 32 + l4 * 8];
#pragma unroll
    for (int m = 0; m < MT; ++m)
#pragma unroll
      for (int n = 0; n < 4; ++n)
        acc[m][n] = __builtin_amdgcn_mfma_f32_16x16x32_bf16(af[m], bfr[n], acc[m][n], 0, 0, 0);
    __syncthreads();
    buf ^= 1;
  }

#pragma unroll
  for (int m = 0; m < MT; ++m) {
    const int rowb = row0 + wr * (BM / 2) + m * 16 + l4 * 4;
#pragma unroll
    for (int n = 0; n < 4; ++n) {
      const int col = col0 + wc * 64 + n * 16 + l15;
#pragma unroll
      for (int j = 0; j < 4; ++j) {
        const int r = rowb + j;
        float v = acc[m][n][j];
        if (EPI == 0) {
          outB[(size_t)r * N + col] = f2bf(v);
        } else if (EPI == 1) {
          v += bias[col];
          outB[(size_t)r * N + col] = f2bf(v > 0.0f ? v : 0.0f);
        } else {
          v += bias[col] + resid[(size_t)r * N + col];
          outF[(size_t)r * N + col] = v;
        }
      }
    }
  }
}

// ---------------- weight transpose f32 -> bf16 ----------------
__global__ __launch_bounds__(256) void transpose_f32_bf16(
    const float* __restrict__ in, u16* __restrict__ out, int R, int C) {
  __shared__ float t[32][33];
  const int c0 = blockIdx.x * 32, r0 = blockIdx.y * 32;
  const int tx = threadIdx.x & 31, ty = threadIdx.x >> 5;
#pragma unroll
  for (int i = 0; i < 4; ++i)
    t[ty + i * 8][tx] = in[(size_t)(r0 + ty + i * 8) * C + c0 + tx];
  __syncthreads();
#pragma unroll
  for (int i = 0; i < 4; ++i)
    out[(size_t)(c0 + ty + i * 8) * R + r0 + tx] = f2bf(t[tx][ty + i * 8]);
}

// ---------------- batched bf16 transpose (strided input, col-offset) ----------------
__global__ __launch_bounds__(256) void transpose_bf16_b(
    const u16* __restrict__ in, u16* __restrict__ out, int R, int C, int rstr, int coff) {
  __shared__ u16 t[32][34];
  const int b = blockIdx.z;
  const u16* pi = in + (size_t)b * R * rstr + coff;
  u16* po = out + (size_t)b * R * C;
  const int c0 = blockIdx.x * 32, r0 = blockIdx.y * 32;
  const int tx = threadIdx.x & 31, ty = threadIdx.x >> 5;
#pragma unroll
  for (int i = 0; i < 4; ++i)
    t[ty + i * 8][tx] = pi[(size_t)(r0 + ty + i * 8) * rstr + c0 + tx];
  __syncthreads();
#pragma unroll
  for (int i = 0; i < 4; ++i)
    po[(size_t)(c0 + ty + i * 8) * R + r0 + tx] = t[tx][ty + i * 8];
}

// ---------------- f32 -> bf16 elementwise ----------------
__global__ __launch_bounds__(256) void cvt_f32_bf16(
    const float* __restrict__ in, u16* __restrict__ out, int n4) {
  const int i = blockIdx.x * 256 + threadIdx.x;
  if (i >= n4) return;
  f32x4 v = *(const f32x4*)&in[(size_t)i * 4];
  s16x4 o;
#pragma unroll
  for (int j = 0; j < 4; ++j) o[j] = (short)f2bf(v[j]);
  *(s16x4*)&out[(size_t)i * 4] = o;
}

// ---------------- LayerNorm over D=1024 ----------------
template <int WB>
__global__ __launch_bounds__(256) void layernorm_k(
    const float* __restrict__ in, const float* __restrict__ gm, const float* __restrict__ bt,
    float* __restrict__ outF, u16* __restrict__ outB) {
  const int row = blockIdx.x;
  const int t = threadIdx.x;
  const float* xr = in + (size_t)row * 1024;
  f32x4 v = *(const f32x4*)&xr[t * 4];
  float s = v[0] + v[1] + v[2] + v[3];
  float s2 = v[0] * v[0] + v[1] * v[1] + v[2] * v[2] + v[3] * v[3];
#pragma unroll
  for (int o = 32; o; o >>= 1) {
    s += __shfl_down(s, o);
    s2 += __shfl_down(s2, o);
  }
  __shared__ float red[8];
  const int lane = t & 63, wv = t >> 6;
  if (lane == 0) { red[wv] = s; red[4 + wv] = s2; }
  __syncthreads();
  s = red[0] + red[1] + red[2] + red[3];
  s2 = red[4] + red[5] + red[6] + red[7];
  const float mu = s * (1.0f / 1024.0f);
  const float var = fmaxf(s2 * (1.0f / 1024.0f) - mu * mu, 0.0f);
  const float rs = rsqrtf(var + 1e-5f);
  f32x4 g4 = *(const f32x4*)&gm[t * 4];
  f32x4 b4 = *(const f32x4*)&bt[t * 4];
  f32x4 ov;
#pragma unroll
  for (int j = 0; j < 4; ++j) ov[j] = (v[j] - mu) * rs * g4[j] + b4[j];
  *(f32x4*)&outF[(size_t)row * 1024 + t * 4] = ov;
  if (WB) {
    s16x4 ob;
#pragma unroll
    for (int j = 0; j < 4; ++j) ob[j] = (short)f2bf(ov[j]);
    *(s16x4*)&outB[(size_t)row * 1024 + t * 4] = ob;
  }
}

// ---------------- mask tile summary: any() over 64x64 tiles ----------------
__global__ __launch_bounds__(256) void mask_summary(
    const u8* __restrict__ mask, u8* __restrict__ msum) {
  const int kt = blockIdx.x, qt = blockIdx.y, b = blockIdx.z;
  const int tid = threadIdx.x;
  __shared__ int any_flag;
  if (tid == 0) any_flag = 0;
  __syncthreads();
  const u8* base = mask + ((size_t)(b * 2048 + qt * 64 + (tid >> 2))) * 2048 + kt * 64 + (tid & 3) * 16;
  const u32x4 v = *(const u32x4*)base;
  if (v[0] | v[1] | v[2] | v[3]) any_flag = 1;
  __syncthreads();
  if (tid == 0) msum[((size_t)b * 32 + qt) * 32 + kt] = (u8)any_flag;
}

// ---------------- flash attention (32 q-rows/wave, reg-cached frags) ----------------
// QKV: [B*S, 3072] bf16 (Q cols 0..1023, K cols 1024..2047); VT: [B*H,64,S] bf16.
// 512 blocks, 4 waves x 32 q-rows (two 16-row groups). K/V frags are q-independent:
// cached in regs, shared by both groups. kv loop unrolled x2 (compile-time buf).
// No min-occupancy bound (R5-proven); fminf scrub cuts any INF->NaN propagation.
__global__ __launch_bounds__(256) void attn_k(
    const u16* __restrict__ QKV, const u16* __restrict__ VT,
    const u8* __restrict__ mask, const u8* __restrict__ msum, u16* __restrict__ out) {
  const int S = 2048, QSTR = 3072, Dm = 1024;
  const int wgid = blockIdx.x;  // 0..511
  const int xcd = wgid & 7, slot = wgid >> 3;
  const int bh = xcd * 4 + (slot >> 4);  // 4 bh per XCD -> 2MB KV resident in L2
  const int qt = slot & 15;
  const int b = bh >> 4, h = bh & 15;
  const int wave = threadIdx.x >> 6, lane = threadIdx.x & 63;
  const int l15 = lane & 15, l4 = lane >> 4;
  const int q0 = qt * 128 + wave * 32;
  const float CE = 0.125f * 1.44269504f;  // 1/sqrt(64) * log2(e)

  __shared__ __align__(16) u16 lK[2][4096];  // [buf][64 rows x 64 cols], XOR-swizzled
  __shared__ __align__(16) u16 lV[2][4096];

  s16x8 qa[2][2];
#pragma unroll
  for (int g = 0; g < 2; ++g) {
    const size_t qoff = (size_t)(b * S + q0 + g * 16 + l15) * QSTR + h * 64;
    qa[g][0] = *(const s16x8*)&QKV[qoff + l4 * 8];
    qa[g][1] = *(const s16x8*)&QKV[qoff + 32 + l4 * 8];
  }

  f32x4 o[2][4] = {};
  float mr[2] = {-1e30f, -1e30f}, lr[2] = {0.0f, 0.0f};
  const u8* mb = mask + (size_t)b * S * S;
  const u8* msb = msum + (size_t)(b * 32 + qt * 2 + (wave >> 1)) * 32;
  const u16* vbase = VT + (size_t)bh * 64 * S;
  const int bS = b * S;

  auto stage = [&](int bi, int kvv) {
#pragma unroll
    for (int c = 0; c < 2; ++c) {
      const int byt = ((c * 4 + wave) * 64 + lane) * 16;  // 0..8191
      const int row = byt >> 7;
      const int cb = (byt & 127) ^ ((row & 7) << 4);
      GLDS16(QKV + (size_t)(bS + kvv + row) * QSTR + 1024 + h * 64 + (cb >> 1),
             &lK[bi][(c * 4 + wave) * 512]);
      GLDS16(vbase + (size_t)row * S + kvv + (cb >> 1),
             &lV[bi][(c * 4 + wave) * 512]);
    }
  };

  auto body = [&](int bi, int kvv) {
    if (kvv + 64 < S) stage(bi ^ 1, kvv + 64);
    const char* kbuf = (const char*)&lK[bi][0];
    const char* vbuf = (const char*)&lV[bi][0];
    // ---- K frags (q-independent, shared by both groups) ----
    s16x8 kf[4][2];
#pragma unroll
    for (int t = 0; t < 4; ++t) {
      const int row = t * 16 + l15;
      const int sw = (row & 7) << 4;
      kf[t][0] = *(const s16x8*)(kbuf + row * 128 + ((l4 * 16) ^ sw));
      kf[t][1] = *(const s16x8*)(kbuf + row * 128 + ((64 + l4 * 16) ^ sw));
    }
    // ---- V frags (q-independent) ----
    s16x4 va[4][4];  // [n][t]
#pragma unroll
    for (int n = 0; n < 4; ++n) {
      const int row = n * 16 + l15;
      const int sw = (row & 7) << 4;
#pragma unroll
      for (int t = 0; t < 4; ++t)
        va[n][t] = *(const s16x4*)(vbuf + row * 128 + ((t * 32 + l4 * 8) ^ sw));
    }
    const int mrow = msb[kvv >> 6];
#pragma unroll
    for (int g = 0; g < 2; ++g) {
      // ---- QK^T (swapped): sc[t] = mfma(K, Q_g) ----
      f32x4 sc[4];
      __builtin_amdgcn_s_setprio(1);
#pragma unroll
      for (int t = 0; t < 4; ++t) {
        f32x4 z = {};
        z = __builtin_amdgcn_mfma_f32_16x16x32_bf16(kf[t][0], qa[g][0], z, 0, 0, 0);
        z = __builtin_amdgcn_mfma_f32_16x16x32_bf16(kf[t][1], qa[g][1], z, 0, 0, 0);
        sc[t] = z;
      }
      __builtin_amdgcn_s_setprio(0);
      // ---- mask (rare slow path via tile summary) ----
      if (mrow) {
#pragma unroll
        for (int t = 0; t < 4; ++t) {
          const uchar4 m4 = *(const uchar4*)&mb[(size_t)(q0 + g * 16 + l15) * S + kvv + t * 16 + l4 * 4];
          if (m4.x) sc[t][0] = -1e30f;
          if (m4.y) sc[t][1] = -1e30f;
          if (m4.z) sc[t][2] = -1e30f;
          if (m4.w) sc[t][3] = -1e30f;
        }
      }
      // ---- INF/NaN scrub (insurance: converts any upstream INF to finite) ----
#pragma unroll
      for (int t = 0; t < 4; ++t)
#pragma unroll
        for (int j = 0; j < 4; ++j) sc[t][j] = fminf(sc[t][j], 1e30f);
      // ---- online softmax with defer-max; max via v_max3 tree ----
      float pm = max3f(sc[0][0], sc[0][1], sc[0][2]);
      pm = max3f(pm, sc[0][3], sc[1][0]);
      pm = max3f(pm, sc[1][1], sc[1][2]);
      pm = max3f(pm, sc[1][3], sc[2][0]);
      pm = max3f(pm, sc[2][1], sc[2][2]);
      pm = max3f(pm, sc[2][3], sc[3][0]);
      pm = max3f(pm, sc[3][1], sc[3][2]);
      pm = fmaxf(pm, sc[3][3]);
      pm = fmaxf(pm, __shfl_xor(pm, 16));
      pm = fmaxf(pm, __shfl_xor(pm, 32));
      if (!__all(pm <= mr[g] + 44.0f)) {  // 44 raw = 8 exp2-units
        const float mn = fmaxf(mr[g], pm);
        const float al = exp2f((mr[g] - mn) * CE);
        mr[g] = mn;
        lr[g] *= al;
#pragma unroll
        for (int n = 0; n < 4; ++n)
#pragma unroll
          for (int j = 0; j < 4; ++j) o[g][n][j] *= al;
      }
      const float mrc = mr[g] * CE;
      float rsum = 0.0f;
#pragma unroll
      for (int t = 0; t < 4; ++t)
#pragma unroll
        for (int j = 0; j < 4; ++j) {
          const float p = exp2f(fmaf(sc[t][j], CE, -mrc));
          sc[t][j] = p;
          rsum += p;
        }
      rsum += __shfl_xor(rsum, 16);
      rsum += __shfl_xor(rsum, 32);
      lr[g] += rsum;
      // ---- pack P into 16x16x16 B-frags (zero cross-lane) ----
      s16x4 pb[4];
#pragma unroll
      for (int t = 0; t < 4; ++t) {
        const u32 lo = cvtpk_bf16(sc[t][0], sc[t][1]);
        const u32 hi = cvtpk_bf16(sc[t][2], sc[t][3]);
        pb[t] = __builtin_bit_cast(s16x4, u32x2{lo, hi});
      }
      // ---- PV: o[g][n] += mfma_16x16x16(V frag, P frag) ----
      __builtin_amdgcn_s_setprio(1);
#pragma unroll
      for (int n = 0; n < 4; ++n)
#pragma unroll
        for (int t = 0; t < 4; ++t)
          o[g][n] = __builtin_amdgcn_mfma_f32_16x16x16bf16_1k(va[n][t], pb[t], o[g][n], 0, 0, 0);
      __builtin_amdgcn_s_setprio(0);
    }
    __syncthreads();  // drains prefetch vmcnt + protects buf swap
  };

  stage(0, 0);
  __syncthreads();
  for (int kv = 0; kv < S; kv += 128) {  // x2 unroll: buf compile-time per body
    body(0, kv);
    body(1, kv + 64);
  }
  // ---- epilogue ----
#pragma unroll
  for (int g = 0; g < 2; ++g) {
    const float inv = lr[g] > 0.0f ? 1.0f / lr[g] : 0.0f;
    const size_t obase = (size_t)(b * S + q0 + g * 16 + l15) * Dm + h * 64;
#pragma unroll
    for (int n = 0; n < 4; ++n) {
      const u32 lo = cvtpk_bf16(o[g][n][0] * inv, o[g][n][1] * inv);
      const u32 hi = cvtpk_bf16(o[g][n][2] * inv, o[g][n][3] * inv);
      *(u32x2*)&out[obase + n * 16 + l4 * 4] = u32x2{lo, hi};
    }
  }
}

extern "C" void kernel_launch(void* const* d_in, const int* in_sizes, int n_in,
                              void* d_out, int out_size, void* d_ws, size_t ws_size,
                              hipStream_t stream) {
  (void)in_sizes; (void)n_in; (void)out_size; (void)ws_size;
  const float* x = (const float*)d_in[0];
  const u8* mask = (const u8*)d_in[1];
  const float* Wq = (const float*)d_in[2];
  const float* Wk = (const float*)d_in[3];
  const float* Wv = (const float*)d_in[4];
  const float* Wo = (const float*)d_in[5];
  const float* bo = (const float*)d_in[6];
  const float* W1 = (const float*)d_in[7];
  const float* b1 = (const float*)d_in[8];
  const float* W2 = (const float*)d_in[9];
  const float* b2 = (const float*)d_in[10];
  const float* g1 = (const float*)d_in[11];
  const float* be1 = (const float*)d_in[12];
  const float* g2 = (const float*)d_in[13];
  const float* be2 = (const float*)d_in[14];
  float* outp = (float*)d_out;

  const int B = 2, S = 2048, D = 1024, FF = 4096;
  const int M = B * S;  // 4096
  char* w = (char*)d_ws;
  const size_t MB = 1024 * 1024;
  u16* wqkvT = (u16*)(w + 0 * MB);    // [3072,1024] bf16   [0,6)
  u16* woT = (u16*)(w + 6 * MB);      // [1024,1024]        [6,8)
  u16* w1T = (u16*)(w + 8 * MB);      // [4096,1024]        [8,16)
  u16* w2T = (u16*)(w + 16 * MB);     // [1024,4096]        [16,24)
  u16* xb  = (u16*)(w + 24 * MB);     // [4096,1024]        [24,32)
  u16* qkv = (u16*)(w + 32 * MB);     // [4096,3072]        [32,56)
  u16* vt  = (u16*)(w + 56 * MB);     // [B*H,64,S]         [56,64)
  float* x0f = (float*)(w + 64 * MB); // [4096,1024] f32    [64,80)
  float* x1f = (float*)(w + 80 * MB); //                    [80,96)
  u16* x1b = (u16*)(w + 96 * MB);     // [4096,1024] bf16   [96,104)
  u8* msum = (u8*)(w + 64 * MB);      // 2 KB, dead before x0f is written
  u16* attn_o = xb;                   // xb dead after QKV gemm
  u16* ff1 = (u16*)(w + 32 * MB);     // [4096,4096] bf16, reuses qkv+vt [32,64)
  float* y0f = x0f;

  // weight prep (Wq/Wk/Wv transposed into one contiguous [3072,1024] block)
  transpose_f32_bf16<<<dim3(32, 32), 256, 0, stream>>>(Wq, wqkvT, 1024, 1024);
  transpose_f32_bf16<<<dim3(32, 32), 256, 0, stream>>>(Wk, wqkvT + 1024 * 1024, 1024, 1024);
  transpose_f32_bf16<<<dim3(32, 32), 256, 0, stream>>>(Wv, wqkvT + 2048 * 1024, 1024, 1024);
  transpose_f32_bf16<<<dim3(32, 32), 256, 0, stream>>>(Wo, woT, 1024, 1024);
  transpose_f32_bf16<<<dim3(128, 32), 256, 0, stream>>>(W1, w1T, 1024, 4096);
  transpose_f32_bf16<<<dim3(32, 128), 256, 0, stream>>>(W2, w2T, 4096, 1024);
  cvt_f32_bf16<<<dim3(M * D / 4 / 256), 256, 0, stream>>>(x, xb, M * D / 4);
  mask_summary<<<dim3(32, 32, 2), 256, 0, stream>>>(mask, msum);

  // fused QKV projection: [4096,1024] @ [3072,1024]^T -> [4096,3072]
  gemm_bt<0, 128><<<dim3(3 * D / 128, M / 128), 256, 0, stream>>>(xb, wqkvT, M, 3 * D, D, nullptr, nullptr, qkv, nullptr);
  // V -> V^T per batch (strided read from qkv cols 2048..3071)
  transpose_bf16_b<<<dim3(32, 64, 2), 256, 0, stream>>>(qkv, vt, 2048, 1024, 3072, 2048);

  // attention: 512 blocks, 4 waves x 32 q-rows
  attn_k<<<dim3(512), 256, 0, stream>>>(qkv, vt, mask, msum, attn_o);

  // Wo projection + bias + residual(x) -- BM=64
  gemm_bt<2, 64><<<dim3(D / 128, M / 64), 256, 0, stream>>>(attn_o, woT, M, D, D, bo, x, nullptr, x0f);
  layernorm_k<1><<<dim3(M), 256, 0, stream>>>(x0f, g1, be1, x1f, x1b);
  gemm_bt<1, 128><<<dim3(FF / 128, M / 128), 256, 0, stream>>>(x1b, w1T, M, FF, D, b1, nullptr, ff1, nullptr);
  gemm_bt<2, 64><<<dim3(D / 128, M / 64), 256, 0, stream>>>(ff1, w2T, M, D, FF, b2, x1f, nullptr, y0f);
  layernorm_k<0><<<dim3(M), 256, 0, stream>>>(y0f, g2, be2, outp, nullptr);
}